// Round 14
// baseline (12647.707 us; speedup 1.0000x reference)
//
#include <hip/hip_runtime.h>
#include <hip/hip_fp16.h>

#define T_LEN 4096
#define HID   256
#define G4    1024
#define DIRSZ (1024 * 128)   // packed weight u32 per direction (4sl*512thr*64w)

typedef unsigned int u32;
typedef unsigned long long u64;
typedef _Float16 half2_t __attribute__((ext_vector_type(2)));

__device__ __forceinline__ float dot2f(u32 w, u32 h, float acc) {
#if __has_builtin(__builtin_amdgcn_fdot2)
    return __builtin_amdgcn_fdot2(__builtin_bit_cast(half2_t, w),
                                  __builtin_bit_cast(half2_t, h), acc, false);
#else
    __half2 wh = __builtin_bit_cast(__half2, w);
    __half2 hh = __builtin_bit_cast(__half2, h);
    float2 wf = __half22float2(wh), hf = __half22float2(hh);
    return acc + wf.x * hf.x + wf.y * hf.y;
#endif
}

// 8-lane tree-sum: DPP quad_perm xor1 (0xB1), xor2 (0x4E), then ds_swizzle
// xor4 (0x101F). 8-lane j-groups start at multiples of 8 -> stay within a
// 32-lane half, so the swizzle is exact. (r12-verified)
__device__ __forceinline__ float qsum8(float v) {
    int i = __builtin_bit_cast(int, v);
    v += __builtin_bit_cast(float,
         __builtin_amdgcn_update_dpp(i, i, 0xB1, 0xF, 0xF, true));
    i = __builtin_bit_cast(int, v);
    v += __builtin_bit_cast(float,
         __builtin_amdgcn_update_dpp(i, i, 0x4E, 0xF, 0xF, true));
    i = __builtin_bit_cast(int, v);
    v += __builtin_bit_cast(float, __builtin_amdgcn_ds_swizzle(i, 0x101F));
    return v;
}

__device__ __forceinline__ u32 pack2(float a, float b) {
    unsigned short lo = __half_as_ushort(__float2half(a));
    unsigned short hi = __half_as_ushort(__float2half(b));
    return ((u32)hi << 16) | (u32)lo;
}

// lgkm-only barrier: never drains vmcnt (global stores/loads keep flying)
__device__ __forceinline__ void step_barrier() {
    asm volatile("s_waitcnt lgkmcnt(0)" ::: "memory");
    __builtin_amdgcn_s_barrier();
    __builtin_amdgcn_sched_barrier(0);
}

// ---------------- zero helper (exchange tags must be 0 at each launch) -------
__global__ void k_zero(u32* __restrict__ p, int n) {
    int q = blockIdx.x * 256 + threadIdx.x;
    if (q < n) p[q] = 0u;
}

// ---------------- transpose: out[k*N+n] = in[n*K+k] ----------------
__global__ void k_transpose(const float* __restrict__ in, float* __restrict__ out,
                            int N, int K) {
    int q = blockIdx.x * 256 + threadIdx.x;
    if (q >= N * K) return;
    int n = q / K, k = q % K;
    out[(size_t)k * N + n] = in[q];
}

// ---------------- pack Whh -> 4-slice own-first layout ----------------------
// Scan thread (slice sl, tid): j=tid>>3 (unit 0..63), q8=tid&7, U=64sl+j.
// regw[widx], widx = g*16 + tb*4 + i  (g=gate row, tb=word block, i=0..3):
//   tb=0 -> own slice; tb=1..3 -> remote slice ps=(tb-1<sl ? tb-1 : tb).
//   h-word w = 32*wsl + 4*q8 + i  ->  W[g*256+U][2w], [2w+1].
// All scan-side regw indices compile-time (rule #20, r9's 90ms lesson).
__global__ void k_pack_s4(const float* __restrict__ W, u32* __restrict__ out) {
    int idx = blockIdx.x * 256 + threadIdx.x;    // 4*512*64 = 131072 total
    if (idx >= 1024 * 128) return;
    int widx = idx & 63;
    int tid  = (idx >> 6) & 511;
    int sl   = idx >> 15;
    int g = widx >> 4, tb = (widx >> 2) & 3, i = widx & 3;
    int j = tid >> 3, q8 = tid & 7;
    int U = 64 * sl + j;
    int wsl = (tb == 0) ? sl : ((tb - 1 < sl) ? tb - 1 : tb);
    int w = 32 * wsl + 4 * q8 + i;
    int row = g * 256 + U;
    out[idx] = pack2(W[row * 256 + 2 * w], W[row * 256 + 2 * w + 1]);
}

// ---------------- generic GEMM: C[M,N] = A[M,K] @ Wt[K,N] (+bias/relu/cosine)
__global__ __launch_bounds__(256) void k_gemm(
    const float* __restrict__ A, const float* __restrict__ Wt,
    const float* __restrict__ bias, const float* __restrict__ norms,
    float* __restrict__ C, int M, int N, int K, int mode) {
    __shared__ float As[16 * 512];
    const int tid = threadIdx.x;
    const int m0 = blockIdx.x * 16;
    const int n  = blockIdx.y * 256 + tid;

    for (int i = tid; i < 16 * K; i += 256) As[i] = A[(size_t)m0 * K + i];
    __syncthreads();

    float acc[16];
#pragma unroll
    for (int m = 0; m < 16; ++m) acc[m] = 0.f;

#pragma unroll 4
    for (int k = 0; k < K; ++k) {
        float w = Wt[(size_t)k * N + n];
#pragma unroll
        for (int m = 0; m < 16; ++m) acc[m] += As[m * K + k] * w;
    }

    float bn = bias ? bias[n] : 0.f;
#pragma unroll
    for (int m = 0; m < 16; ++m) {
        float v = acc[m] + bn;
        if (mode == 1) v = fmaxf(v, 0.f);
        if (mode == 2) {
            float d = norms[m0 + m] * norms[n];
            v = 1.f - fmaxf(acc[m] / d, 1e-6f);
        }
        C[(size_t)(m0 + m) * N + n] = v;
    }
}

// ---------------- row norms of e (4096 x 256) ----------------
__global__ void k_norms(const float* __restrict__ e, float* __restrict__ norms) {
    int i = blockIdx.x, lane = threadIdx.x;
    float s = 0.f;
    for (int k = lane; k < 256; k += 64) { float v = e[i * 256 + k]; s += v * v; }
    for (int off = 32; off; off >>= 1) s += __shfl_down(s, off);
    if (lane == 0) norms[i] = sqrtf(s);
}

// ---------------- 4-slice x issue-early scan (v14) ----------------
// Grid 8 = 2 dirs x 4 slices (dir=bid&1, s=bid>>1), 512 threads.
// Thread (j=tid>>3, q8=tid&7) owns 4 gate-rows of unit U=64s+j, 16 h-words
// (4 own-slice + 4 per remote slice), 64 weight u32 in VGPRs.
// Schedule (r13's issue-early poll + r12's 8-CU split):
//   top: issue 192 remote poll loads (u32 tag16|h16, relaxed agent);
//   phase1: own-slice dots (1 b128, 16 dots) - overlaps poll RTT;
//   check tag==t (rare spin), write remote f16 into hb[cur]; [bar]
//   phase2: remote dots (3 b128, 48 dots); qsum8 x4; gates in-thread;
//   q8==0: own h -> hb[nxt] + publish tag t+1 (fire-and-forget);
//   q8==1: hout; [bar]
// Bank pattern: each read's 8 q8-lanes x 4 words tile all 32 banks once ->
// conflict-free; j-groups broadcast. Safety: parity slots + lockstep skew<=1.
__global__ __launch_bounds__(512, 2) void k_scan_s4(
    const float* __restrict__ xs, const u32* __restrict__ rp,
    u32* __restrict__ ex, float* __restrict__ hout) {
    __shared__ alignas(16) u32 hb[2][128];   // h(t-1)/h(t), f16x2 packed

    const int bid = blockIdx.x;
    const int dir = bid & 1;
    const int s   = bid >> 1;        // slice 0..3
    const int tid = threadIdx.x;
    const int j   = tid >> 3;        // unit within slice, 0..63
    const int q8  = tid & 7;
    const int gq  = q8 & 3;          // xs gate-row this lane fetches
    const int U   = 64 * s + j;      // unit within direction, 0..255

    // remote slice order and their h word-block bases (runtime, address-only)
    int ps0 = (0 < s) ? 0 : 1;
    int ps1 = (1 < s) ? 1 : 2;       // works for s=0..3: skips s
    int ps2 = (2 < s) ? 2 : 3;
    // (s=0 -> 1,2,3 ; s=1 -> 0,2,3 ; s=2 -> 0,1,3 ; s=3 -> 0,1,2)

    xs += (size_t)dir * (T_LEN * G4);
    rp += (size_t)dir * DIRSZ;
    u32* exd = ex + dir * 512;       // [parity(2)][unit(256)] u32

    u32 regw[64];
    {
        const uint4* rp4 = (const uint4*)(rp + (size_t)(s * 512 + tid) * 64);
#pragma unroll
        for (int p = 0; p < 16; ++p) {
            uint4 v = rp4[p];
            regw[4 * p + 0] = v.x; regw[4 * p + 1] = v.y;
            regw[4 * p + 2] = v.z; regw[4 * p + 3] = v.w;
        }
    }
    if (tid < 128) { hb[0][tid] = 0u; hb[1][tid] = 0u; }
    // remote-unit index for this thread's poll duty (tid<192)
    const int U2 = (tid < 64 * s) ? tid : tid + 64;
    float cst = 0.f;
    __syncthreads();

    int tt = dir ? (T_LEN - 1) : 0;
    const int stp = dir ? -1 : 1;
    float xa = xs[(size_t)tt * G4 + (gq * 256 + U)];

    for (int t = 0; t < T_LEN; ++t) {
        const int cur = t & 1, nxt = cur ^ 1;
        int tn = (t + 1 < T_LEN) ? tt + stp : tt;

        // issue-early remote poll load (tag t expected; published last iter)
        u32 pv = 0;
        if (t > 0 && tid < 192)
            pv = __hip_atomic_load(&exd[cur * 256 + U2],
                                   __ATOMIC_RELAXED, __HIP_MEMORY_SCOPE_AGENT);

        float acc0 = (q8 == 0) ? xa : 0.f;   // i
        float acc1 = (q8 == 1) ? xa : 0.f;   // f
        float acc2 = (q8 == 2) ? xa : 0.f;   // g
        float acc3 = (q8 == 3) ? xa : 0.f;   // o
        xa = xs[(size_t)tn * G4 + (gq * 256 + U)];    // prefetch (never drained)

        // ---- phase 1: own-slice dots (1 b128, 16 dots) ----
        {
            uint4 hv4 = *(const uint4*)&hb[cur][32 * s + 4 * q8];
            u32 hh[4] = { hv4.x, hv4.y, hv4.z, hv4.w };
#pragma unroll
            for (int i = 0; i < 4; ++i) {
                acc0 = dot2f(regw[i],       hh[i], acc0);
                acc1 = dot2f(regw[16 + i],  hh[i], acc1);
                acc2 = dot2f(regw[32 + i],  hh[i], acc2);
                acc3 = dot2f(regw[48 + i],  hh[i], acc3);
            }
        }

        // check (RTT overlapped by phase1 + loop top) + LDS-write remote h
        if (t > 0 && tid < 192) {
            while ((pv >> 16) != (u32)t)
                pv = __hip_atomic_load(&exd[cur * 256 + U2],
                                       __ATOMIC_RELAXED, __HIP_MEMORY_SCOPE_AGENT);
            ((__half*)hb[cur])[U2] =
                __ushort_as_half((unsigned short)(pv & 0xffffu));
        }
        step_barrier();

        // ---- phase 2: remote-slice dots (3 b128, 48 dots) ----
        {
            uint4 hv4 = *(const uint4*)&hb[cur][32 * ps0 + 4 * q8];
            u32 hh[4] = { hv4.x, hv4.y, hv4.z, hv4.w };
#pragma unroll
            for (int i = 0; i < 4; ++i) {
                acc0 = dot2f(regw[4 + i],       hh[i], acc0);
                acc1 = dot2f(regw[20 + i],  hh[i], acc1);
                acc2 = dot2f(regw[36 + i],  hh[i], acc2);
                acc3 = dot2f(regw[52 + i],  hh[i], acc3);
            }
        }
        {
            uint4 hv4 = *(const uint4*)&hb[cur][32 * ps1 + 4 * q8];
            u32 hh[4] = { hv4.x, hv4.y, hv4.z, hv4.w };
#pragma unroll
            for (int i = 0; i < 4; ++i) {
                acc0 = dot2f(regw[8 + i],       hh[i], acc0);
                acc1 = dot2f(regw[24 + i],  hh[i], acc1);
                acc2 = dot2f(regw[40 + i],  hh[i], acc2);
                acc3 = dot2f(regw[56 + i],  hh[i], acc3);
            }
        }
        {
            uint4 hv4 = *(const uint4*)&hb[cur][32 * ps2 + 4 * q8];
            u32 hh[4] = { hv4.x, hv4.y, hv4.z, hv4.w };
#pragma unroll
            for (int i = 0; i < 4; ++i) {
                acc0 = dot2f(regw[12 + i],      hh[i], acc0);
                acc1 = dot2f(regw[28 + i],  hh[i], acc1);
                acc2 = dot2f(regw[44 + i],  hh[i], acc2);
                acc3 = dot2f(regw[60 + i],  hh[i], acc3);
            }
        }

        // 8-lane tree-sum -> every lane holds full z for unit U
        float zi = qsum8(acc0), zf = qsum8(acc1);
        float zg = qsum8(acc2), zo = qsum8(acc3);

        // gates in-thread (redundant x8, no divergence)
        float si = 1.f / (1.f + __expf(-zi));
        float sf = 1.f / (1.f + __expf(-zf));
        float so = 1.f / (1.f + __expf(-zo));
        float tg = 1.f - 2.f / (__expf(2.f * zg) + 1.f);
        cst = sf * cst + si * tg;
        float th = 1.f - 2.f / (__expf(2.f * cst) + 1.f);
        float hv = so * th;

        if (q8 == 0) {
            unsigned short h16 = __half_as_ushort(__float2half(hv));
            ((__half*)hb[nxt])[U] = __ushort_as_half(h16);
            __hip_atomic_store(&exd[nxt * 256 + U],
                               ((u32)(t + 1) << 16) | (u32)h16,
                               __ATOMIC_RELAXED, __HIP_MEMORY_SCOPE_AGENT);
        }
        if (q8 == 1)                         // unquantized h -> hout
            hout[(size_t)tt * 512 + dir * 256 + U] = hv;

        step_barrier();
        tt = tn;
    }
}

// ---------------- launcher ----------------
extern "C" void kernel_launch(void* const* d_in, const int* in_sizes, int n_in,
                              void* d_out, int out_size, void* d_ws, size_t ws_size,
                              hipStream_t stream) {
    const float* x       = (const float*)d_in[0];
    const float* wih_l0f = (const float*)d_in[1];
    const float* whh_l0f = (const float*)d_in[2];
    const float* b_l0f   = (const float*)d_in[3];
    const float* wih_l0b = (const float*)d_in[4];
    const float* whh_l0b = (const float*)d_in[5];
    const float* b_l0b   = (const float*)d_in[6];
    const float* wih_l1f = (const float*)d_in[7];
    const float* whh_l1f = (const float*)d_in[8];
    const float* b_l1f   = (const float*)d_in[9];
    const float* wih_l1b = (const float*)d_in[10];
    const float* whh_l1b = (const float*)d_in[11];
    const float* b_l1b   = (const float*)d_in[12];
    const float* fc1_w   = (const float*)d_in[13];
    const float* fc1_b   = (const float*)d_in[14];
    const float* fc2_w   = (const float*)d_in[15];
    const float* fc2_b   = (const float*)d_in[16];
    float* outp = (float*)d_out;

    char* ws = (char*)d_ws;
    size_t off = 0;
    auto alloc = [&](size_t nbytes) {
        char* p = ws + off;
        off += (nbytes + 255) & ~(size_t)255;
        return p;
    };
    float* xs0   = (float*)alloc((size_t)2 * T_LEN * G4 * 4);
    float* xs1   = (float*)alloc((size_t)2 * T_LEN * G4 * 4);
    float* h1    = (float*)alloc((size_t)T_LEN * 512 * 4);
    float* h2    = (float*)alloc((size_t)T_LEN * 512 * 4);
    float* zb    = (float*)alloc((size_t)T_LEN * 256 * 4);
    float* eb    = (float*)alloc((size_t)T_LEN * 256 * 4);
    float* etb   = (float*)alloc((size_t)T_LEN * 256 * 4);
    float* nrm   = (float*)alloc((size_t)T_LEN * 4);
    float* wt0f  = (float*)alloc((size_t)128 * 1024 * 4);
    float* wt0b  = (float*)alloc((size_t)128 * 1024 * 4);
    float* wt1f  = (float*)alloc((size_t)512 * 1024 * 4);
    float* wt1b  = (float*)alloc((size_t)512 * 1024 * 4);
    float* wtf1  = (float*)alloc((size_t)512 * 256 * 4);
    float* wtf2  = (float*)alloc((size_t)256 * 256 * 4);
    u32*   rpm0  = (u32*)alloc((size_t)2 * DIRSZ * 4);
    u32*   rpm1  = (u32*)alloc((size_t)2 * DIRSZ * 4);
    u32*   exA   = (u32*)alloc((size_t)1024 * 4);  // 2dir x 2par x 256 units
    u32*   exB   = (u32*)alloc((size_t)1024 * 4);

    // reset exchange tags (every launch / graph replay); exA,exB contiguous
    k_zero<<<8, 256, 0, stream>>>(exA, 2048);

    // weight transposes
    k_transpose<<<(1024 * 128 + 255) / 256, 256, 0, stream>>>(wih_l0f, wt0f, 1024, 128);
    k_transpose<<<(1024 * 128 + 255) / 256, 256, 0, stream>>>(wih_l0b, wt0b, 1024, 128);
    k_transpose<<<(1024 * 512 + 255) / 256, 256, 0, stream>>>(wih_l1f, wt1f, 1024, 512);
    k_transpose<<<(1024 * 512 + 255) / 256, 256, 0, stream>>>(wih_l1b, wt1b, 1024, 512);
    k_transpose<<<(256 * 512 + 255) / 256, 256, 0, stream>>>(fc1_w, wtf1, 256, 512);
    k_transpose<<<(256 * 256 + 255) / 256, 256, 0, stream>>>(fc2_w, wtf2, 256, 256);

    // recurrent weight packs (4-slice own-first layout)
    k_pack_s4<<<512, 256, 0, stream>>>(whh_l0f, rpm0);
    k_pack_s4<<<512, 256, 0, stream>>>(whh_l0b, rpm0 + DIRSZ);
    k_pack_s4<<<512, 256, 0, stream>>>(whh_l1f, rpm1);
    k_pack_s4<<<512, 256, 0, stream>>>(whh_l1b, rpm1 + DIRSZ);

    dim3 g1024(T_LEN / 16, 4);
    // layer 0 input projections
    k_gemm<<<g1024, 256, 0, stream>>>(x, wt0f, b_l0f, nullptr, xs0, T_LEN, 1024, 128, 0);
    k_gemm<<<g1024, 256, 0, stream>>>(x, wt0b, b_l0b, nullptr, xs0 + (size_t)T_LEN * G4, T_LEN, 1024, 128, 0);
    // layer 0 scan (2 dirs x 4 slices on 8 CUs)
    k_scan_s4<<<8, 512, 0, stream>>>(xs0, rpm0, exA, h1);
    // layer 1 input projections
    k_gemm<<<g1024, 256, 0, stream>>>(h1, wt1f, b_l1f, nullptr, xs1, T_LEN, 1024, 512, 0);
    k_gemm<<<g1024, 256, 0, stream>>>(h1, wt1b, b_l1b, nullptr, xs1 + (size_t)T_LEN * G4, T_LEN, 1024, 512, 0);
    // layer 1 scan
    k_scan_s4<<<8, 512, 0, stream>>>(xs1, rpm1, exB, h2);
    // FC head
    k_gemm<<<dim3(T_LEN / 16, 1), 256, 0, stream>>>(h2, wtf1, fc1_b, nullptr, zb, T_LEN, 256, 512, 1);
    k_gemm<<<dim3(T_LEN / 16, 1), 256, 0, stream>>>(zb, wtf2, fc2_b, nullptr, eb, T_LEN, 256, 256, 0);
    // cosine-similarity output
    k_transpose<<<(T_LEN * 256 + 255) / 256, 256, 0, stream>>>(eb, etb, T_LEN, 256);
    k_norms<<<T_LEN, 64, 0, stream>>>(eb, nrm);
    k_gemm<<<dim3(T_LEN / 16, T_LEN / 256), 256, 0, stream>>>(eb, etb, nullptr, nrm, outp, T_LEN, T_LEN, 256, 2);
}